// Round 5
// baseline (361.668 us; speedup 1.0000x reference)
//
#include <hip/hip_runtime.h>
#include <cmath>

// Problem constants
#define BB 16384
#define DD 256
#define UU 256
#define TT 32
#define MM 64

// ws layout (float offsets)
#define WS_ALPHA 0
#define WS_BETA  16384
#define WS_M1    32768
#define WS_M2    33024
#define WS_V1    33280
#define WS_V2    34304
#define WS_PART1 35328
#define WS_PART2 68096
#define WS_BF16_BYTE 403456   // = 100864 floats * 4
// bf16 region (shorts):
//   Ahi[16 kc][16384 m][32], Alo same (16.78 MB each)
//   Bg [8 nb][16 kc][10240]  (2.62 MB)
// A row layout (32 shorts per (kc,m)): pos = s*16 + h*8 + j  <->  k = kc*32 + s*16 + h*4 + (j&3) + 8*(j>>2)
// B image per (nb,kc), 10240 shorts: [half hi/lo:5120][g*2+s:512][lane:8]
//   granule (half,g,s,lane) holds j=0..7 with col u = nb*32+(lane&31), hl=lane>>5,
//   k = kc*32 + s*16 + hl*4 + (j&3) + 8*(j>>2)

typedef short bf16x8 __attribute__((ext_vector_type(8)));
typedef float f32x16 __attribute__((ext_vector_type(16)));

__device__ __forceinline__ float hsig(float x) {
    return fminf(1.0f, fmaxf(0.0f, fmaf(0.2f, x, 0.5f)));
}
__device__ __forceinline__ short f2bf(float x) {
    unsigned u = __float_as_uint(x);
    unsigned r = (u + 0x7fffu + ((u >> 16) & 1u)) >> 16;
    return (short)r;
}
__device__ __forceinline__ float bf2f(short h) {
    return __uint_as_float(((unsigned)(unsigned short)h) << 16);
}

// ---- D1: fused prep: conv_a | conv_b | coef | colsum-partials ----
__global__ void k_prep(const float* __restrict__ inputs, const float* __restrict__ h1,
                       const float* __restrict__ h2,
                       const int* __restrict__ neighbors, const int* __restrict__ mapping,
                       const int* __restrict__ revmap, const int* __restrict__ timep,
                       const float* __restrict__ W, const float* __restrict__ U,
                       const float* __restrict__ Un,
                       short* __restrict__ Ahi, short* __restrict__ Alo,
                       short* __restrict__ Bg,
                       float* __restrict__ alpha, float* __restrict__ beta,
                       float* __restrict__ part1, float* __restrict__ part2) {
    int blk = blockIdx.x;
    int tid = threadIdx.x;
    if (blk < 4096) {
        // conv_a
        int q = tid & 3;           // q = s*2 + h
        int m = (blk & 255) * 64 + (tid >> 2);
        int kc = blk >> 8;
        int s = q >> 1, h = q & 1;
        int k0 = kc * 32 + s * 16 + h * 4;    // global k of j=0
        const float* src = (k0 < 256) ? (inputs + m * 256 + k0) : (h1 + m * 256 + k0 - 256);
        float4 x0 = *(const float4*)(src);
        float4 x1 = *(const float4*)(src + 8);
        float xs[8] = {x0.x, x0.y, x0.z, x0.w, x1.x, x1.y, x1.z, x1.w};
        bf16x8 hv, lv;
        #pragma unroll
        for (int j = 0; j < 8; j++) {
            short hh = f2bf(xs[j]);
            hv[j] = hh;
            lv[j] = f2bf(xs[j] - bf2f(hh));
        }
        long doff = ((long)kc * 16384 + m) * 32 + q * 8;   // q*8 = s*16 + h*8
        *(bf16x8*)(Ahi + doff) = hv;
        *(bf16x8*)(Alo + doff) = lv;
    } else if (blk < 4416) {
        // conv_b: one thread per (img, g, s, lane), writes hi+lo granules
        int t = (blk - 4096) * 256 + tid;    // 0..81919
        int lane = t & 63;
        int rest = t >> 6;                   // 0..1279
        int gs = rest % 10;                  // g*2+s
        int img = rest / 10;                 // nb*16+kc
        int g = gs >> 1, s = gs & 1;
        int nb = img >> 4, kc = img & 15;
        int u = nb * 32 + (lane & 31);
        int hl = lane >> 5;
        int c = (g < 4) ? g * 256 + u : 256 + u;
        bf16x8 hv, lv;
        #pragma unroll
        for (int j = 0; j < 8; j++) {
            int k = kc * 32 + s * 16 + hl * 4 + (j & 3) + 8 * (j >> 2);
            const float* sp;
            if (k < 256) sp = W + k * 1024 + c;
            else         sp = ((g < 4) ? U : Un) + (k - 256) * 1024 + c;
            float x = *sp;
            short hh = f2bf(x);
            hv[j] = hh;
            lv[j] = f2bf(x - bf2f(hh));
        }
        short* dst = Bg + (long)img * 10240 + gs * 512 + lane * 8;
        *(bf16x8*)dst = hv;              // hi half
        *(bf16x8*)(dst + 5120) = lv;     // lo half
    } else if (blk < 8512) {
        // coef
        int lane = tid & 63;
        int wid  = tid >> 6;
        int b = (blk - 4416) * 4 + wid;
        int t = timep[0];
        int p = revmap[b * TT + t];
        int ng = neighbors[(b * TT + p) * MM + lane];
        int mp = mapping[b * MM + lane];
        int cnt = ng;
        int cp  = (mp < t) ? ng : 0;
        #pragma unroll
        for (int off = 32; off > 0; off >>= 1) {
            cnt += __shfl_xor(cnt, off);
            cp  += __shfl_xor(cp, off);
        }
        if (lane == 0) {
            float a = 0.f, be = 0.f;
            if (cnt > 0) {
                float inv = 1.0f / (float)cnt;
                a  = (float)cp * inv;
                be = (float)(cnt - cp) * inv;
            }
            alpha[b] = a;
            beta[b]  = be;
        }
    } else {
        // colsum partials
        int p = blk - 8512;        // 0..127
        int r0 = p * 128;
        float s1 = 0.f, s2 = 0.f;
        for (int r = 0; r < 128; r++) {
            s1 += h1[(r0 + r) * UU + tid];
            s2 += h2[(r0 + r) * UU + tid];
        }
        part1[p * 256 + tid] = s1;
        part2[p * 256 + tid] = s2;
    }
}

// ---- D2: reduce partials -> hs; v1/v2 = hs @ Un; zero m1/m2 ----
__global__ void k_mid(const float* __restrict__ Un,
                      const float* __restrict__ part1, const float* __restrict__ part2,
                      float* __restrict__ v1, float* __restrict__ v2,
                      float* __restrict__ m12) {
    __shared__ float sh1[256], sh2[256];
    int tid = threadIdx.x;
    if (blockIdx.x == 0 && tid < 512) m12[tid] = 0.f;
    float s1 = 0.f, s2 = 0.f;
    #pragma unroll 8
    for (int p = 0; p < 128; p++) {
        s1 += part1[p * 256 + tid];
        s2 += part2[p * 256 + tid];
    }
    sh1[tid] = s1;
    sh2[tid] = s2;
    __syncthreads();
    int j = blockIdx.x * 256 + tid;
    float a1 = 0.f, a2 = 0.f;
    for (int k = 0; k < 256; k++) {
        float w = Un[k * 1024 + j];
        a1 = fmaf(sh1[k], w, a1);
        a2 = fmaf(sh2[k], w, a2);
    }
    v1[j] = a1;
    v2[j] = a2;
}

// ---- D3: 32x32x16 MFMA GEMM + fused LSTM epilogue ----
// grid (128 mb, 8 nb), 256 threads = 4 waves; wave tile 32 rows x 160 virt (5 gates x 32 units)
#define STAGE_B(KC, BUF) { \
    const char* _s = (const char*)(Bt + (long)(KC) * 10240); \
    char* _d = (char*)(&Bs[BUF][0]); \
    _Pragma("unroll") \
    for (int _c = 0; _c < 5; _c++) { \
        int _u = wv * 5120 + _c * 1024; \
        __builtin_amdgcn_global_load_lds( \
            (const __attribute__((address_space(1))) void*)(_s + _u + lane * 16), \
            (__attribute__((address_space(3))) void*)(_d + _u), 16, 0, 0); \
    } }

__global__ __launch_bounds__(256) void k_gemm_mfma(
    const short* __restrict__ Ahi, const short* __restrict__ Alo,
    const short* __restrict__ Bg,
    const float* __restrict__ c1p, const float* __restrict__ c2p,
    const float* __restrict__ bias,
    const float* __restrict__ alpha, const float* __restrict__ beta,
    const float* __restrict__ v1, const float* __restrict__ v2,
    float* __restrict__ m1, float* __restrict__ m2,
    float* __restrict__ out_h, float* __restrict__ out_mem)
{
    __shared__ short Bs[2][10240];   // 2 x 20 KB, granule-linear (conflict-free b128)

    const int tid = threadIdx.x;
    const int lane = tid & 63;
    const int wv = tid >> 6;
    const int mb = blockIdx.x;
    const int nb = blockIdx.y;
    const int m0 = mb * 128;
    const short* Bt = Bg + (long)nb * 163840;

    const int col = lane & 31;           // unit within block / A row within wave tile
    const int hl = lane >> 5;
    const int m = m0 + wv * 32 + col;
    const long abase = (long)m * 32 + hl * 8;   // + kc*524288 ; +16 for s=1

    f32x16 acc[5];
    #pragma unroll
    for (int g = 0; g < 5; g++)
        #pragma unroll
        for (int r = 0; r < 16; r++) acc[g][r] = 0.f;

    STAGE_B(0, 0);
    bf16x8 ah0 = *(const bf16x8*)(Ahi + abase);
    bf16x8 ah1 = *(const bf16x8*)(Ahi + abase + 16);
    bf16x8 al0 = *(const bf16x8*)(Alo + abase);
    bf16x8 al1 = *(const bf16x8*)(Alo + abase + 16);

    for (int kc = 0; kc < 16; kc++) {
        __syncthreads();                         // B(kc) staged
        bf16x8 nh0, nh1, nl0, nl1;
        if (kc + 1 < 16) {
            STAGE_B(kc + 1, (kc + 1) & 1);
            long ab = abase + (long)(kc + 1) * 524288;
            nh0 = *(const bf16x8*)(Ahi + ab);
            nh1 = *(const bf16x8*)(Ahi + ab + 16);
            nl0 = *(const bf16x8*)(Alo + ab);
            nl1 = *(const bf16x8*)(Alo + ab + 16);
        }

        const char* bp = (const char*)Bs + (kc & 1) * 20480 + lane * 16;
        #pragma unroll
        for (int g = 0; g < 5; g++) {
            bf16x8 bh0 = *(const bf16x8*)(bp + (g * 2 + 0) * 1024);
            bf16x8 bh1 = *(const bf16x8*)(bp + (g * 2 + 1) * 1024);
            bf16x8 bl0 = *(const bf16x8*)(bp + 10240 + (g * 2 + 0) * 1024);
            bf16x8 bl1 = *(const bf16x8*)(bp + 10240 + (g * 2 + 1) * 1024);
            acc[g] = __builtin_amdgcn_mfma_f32_32x32x16_bf16(ah0, bh0, acc[g], 0, 0, 0);
            acc[g] = __builtin_amdgcn_mfma_f32_32x32x16_bf16(ah1, bh1, acc[g], 0, 0, 0);
            acc[g] = __builtin_amdgcn_mfma_f32_32x32x16_bf16(al0, bh0, acc[g], 0, 0, 0);
            acc[g] = __builtin_amdgcn_mfma_f32_32x32x16_bf16(al1, bh1, acc[g], 0, 0, 0);
            acc[g] = __builtin_amdgcn_mfma_f32_32x32x16_bf16(ah0, bl0, acc[g], 0, 0, 0);
            acc[g] = __builtin_amdgcn_mfma_f32_32x32x16_bf16(ah1, bl1, acc[g], 0, 0, 0);
        }
        if (kc + 1 < 16) { ah0 = nh0; ah1 = nh1; al0 = nl0; al1 = nl1; }
    }

    // ---- fused epilogue; C/D: col=lane&31, row=(r&3)+8*(r>>2)+4*(lane>>5) ----
    int u = nb * 32 + col;
    float bi = bias[u], bfv = bias[256 + u], bc = bias[512 + u], bo = bias[768 + u];
    float v1i = v1[u], v1c = v1[512 + u], v1o = v1[768 + u];
    float v2i = v2[u], v2c = v2[512 + u], v2o = v2[768 + u];

    float pm1 = 0.f, pm2 = 0.f;
    #pragma unroll
    for (int r = 0; r < 16; r++) {
        int row = (r & 3) + 8 * (r >> 2) + 4 * hl;
        int b = m0 + wv * 32 + row;
        float al = alpha[b], be = beta[b];
        float c1 = c1p[b * 256 + u];
        float c2 = c2p[b * 256 + u];
        float zi  = acc[0][r] + bi + al * v1i + be * v2i;
        float zf  = acc[1][r] + bfv;
        float zc  = acc[2][r] + bc + al * v1c + be * v2c;
        float zo  = acc[3][r] + bo + al * v1o + be * v2o;
        float zfa = acc[4][r] + bfv;
        float ig = hsig(zi), fg = hsig(zf), og = hsig(zo), fav = hsig(zfa);
        float cg = tanhf(zc);
        out_mem[b * 256 + u] = fg * c1 + ig * cg;
        out_h[b * 256 + u]  = og;
        pm1 += fav * c1;
        pm2 += fav * c2;
    }

    // lanes l and l^32 share the same unit; reduce, then cross-wave via LDS
    pm1 += __shfl_xor(pm1, 32);
    pm2 += __shfl_xor(pm2, 32);
    __syncthreads();
    float* red = (float*)&Bs[0][0];   // [wave][d][u] = 4*2*32 floats
    if (hl == 0) {
        red[(wv * 2 + 0) * 32 + col] = pm1;
        red[(wv * 2 + 1) * 32 + col] = pm2;
    }
    __syncthreads();
    if (tid < 64) {
        int d = tid >> 5, ui = tid & 31;
        float s = 0.f;
        #pragma unroll
        for (int w = 0; w < 4; w++) s += red[(w * 2 + d) * 32 + ui];
        atomicAdd(((d == 0) ? m1 : m2) + nb * 32 + ui, s);
    }
}

// ---- D4: memory = alpha*m1 + beta*m2 + mem_partial ; h = o * tanh(memory) ----
__global__ void k_final(const float* __restrict__ alpha, const float* __restrict__ beta,
                        const float* __restrict__ m1, const float* __restrict__ m2,
                        float* __restrict__ out_h, float* __restrict__ out_mem) {
    int idx = blockIdx.x * 256 + threadIdx.x;
    int b  = idx >> 6;
    int uv = idx & 63;
    float4 mp = ((const float4*)out_mem)[idx];
    float4 ov = ((const float4*)out_h)[idx];
    float al = alpha[b], be = beta[b];
    float4 m1v = ((const float4*)m1)[uv];
    float4 m2v = ((const float4*)m2)[uv];
    float4 mem, h;
    mem.x = fmaf(al, m1v.x, fmaf(be, m2v.x, mp.x)); h.x = ov.x * tanhf(mem.x);
    mem.y = fmaf(al, m1v.y, fmaf(be, m2v.y, mp.y)); h.y = ov.y * tanhf(mem.y);
    mem.z = fmaf(al, m1v.z, fmaf(be, m2v.z, mp.z)); h.z = ov.z * tanhf(mem.z);
    mem.w = fmaf(al, m1v.w, fmaf(be, m2v.w, mp.w)); h.w = ov.w * tanhf(mem.w);
    ((float4*)out_mem)[idx] = mem;
    ((float4*)out_h)[idx]   = h;
}

extern "C" void kernel_launch(void* const* d_in, const int* in_sizes, int n_in,
                              void* d_out, int out_size, void* d_ws, size_t ws_size,
                              hipStream_t stream) {
    const float* inputs   = (const float*)d_in[0];
    const float* h_tm1    = (const float*)d_in[1];
    const float* c_tm1    = (const float*)d_in[2];
    const float* h_tm2    = (const float*)d_in[3];
    const float* c_tm2    = (const float*)d_in[4];
    const int*   neighbors= (const int*)d_in[5];
    const int*   mapping  = (const int*)d_in[6];
    const int*   revmap   = (const int*)d_in[7];
    const int*   timep    = (const int*)d_in[8];
    const float* W        = (const float*)d_in[9];
    const float* Uw       = (const float*)d_in[10];
    const float* Un       = (const float*)d_in[11];
    const float* bias     = (const float*)d_in[12];

    float* ws    = (float*)d_ws;
    float* alpha = ws + WS_ALPHA;
    float* beta  = ws + WS_BETA;
    float* m1    = ws + WS_M1;
    float* m2    = ws + WS_M2;
    float* v1    = ws + WS_V1;
    float* v2    = ws + WS_V2;
    float* part1 = ws + WS_PART1;
    float* part2 = ws + WS_PART2;

    short* Ahi = (short*)((char*)d_ws + WS_BF16_BYTE);
    short* Alo = Ahi + 8388608;
    short* Bg  = Alo + 8388608;

    float* out_h   = (float*)d_out;
    float* out_mem = out_h + BB * UU;

    k_prep<<<8640, 256, 0, stream>>>(inputs, h_tm1, h_tm2, neighbors, mapping, revmap,
                                     timep, W, Uw, Un, Ahi, Alo, Bg, alpha, beta,
                                     part1, part2);
    k_mid<<<4, 256, 0, stream>>>(Un, part1, part2, v1, v2, m1);

    dim3 g3(128, 8);
    k_gemm_mfma<<<g3, 256, 0, stream>>>(Ahi, Alo, Bg, c_tm1, c_tm2, bias,
                                        alpha, beta, v1, v2, m1, m2, out_h, out_mem);

    k_final<<<BB * UU / 4 / 256, 256, 0, stream>>>(alpha, beta, m1, m2, out_h, out_mem);
}

// Round 7
// 361.110 us; speedup vs baseline: 1.0015x; 1.0015x over previous
//
#include <hip/hip_runtime.h>
#include <cmath>

// Problem constants
#define BB 16384
#define DD 256
#define UU 256
#define TT 32
#define MM 64

// ws layout (float offsets)
#define WS_ALPHA 0
#define WS_BETA  16384
#define WS_M1    32768
#define WS_M2    33024
#define WS_V1    33280
#define WS_V2    34304
#define WS_PART1 35328
#define WS_PART2 68096
#define WS_BF16_BYTE 403456   // = 100864 floats * 4
// bf16 region (shorts):
//   Ahi[16 kc][16384 m][32], Alo same (16.78 MB each)
//   Bg [8 nb][16 kc][10240]  (2.62 MB)
// A row layout (32 shorts per (kc,m)): pos = s*16 + h*8 + j  <->  k = kc*32 + s*16 + h*4 + (j&3) + 8*(j>>2)
// B image per (nb,kc), 10240 shorts: [half hi/lo:5120][g*2+s:512][lane:8]
//   granule (half,g,s,lane) holds j=0..7 with col u = nb*32+(lane&31), hl=lane>>5,
//   k = kc*32 + s*16 + hl*4 + (j&3) + 8*(j>>2)

typedef short bf16x8 __attribute__((ext_vector_type(8)));
typedef float f32x16 __attribute__((ext_vector_type(16)));

__device__ __forceinline__ float hsig(float x) {
    return fminf(1.0f, fmaxf(0.0f, fmaf(0.2f, x, 0.5f)));
}
__device__ __forceinline__ short f2bf(float x) {
    unsigned u = __float_as_uint(x);
    unsigned r = (u + 0x7fffu + ((u >> 16) & 1u)) >> 16;
    return (short)r;
}
__device__ __forceinline__ float bf2f(short h) {
    return __uint_as_float(((unsigned)(unsigned short)h) << 16);
}

// ---- D1: fused prep: conv_a | conv_b | coef | colsum-partials ----
__global__ void k_prep(const float* __restrict__ inputs, const float* __restrict__ h1,
                       const float* __restrict__ h2,
                       const int* __restrict__ neighbors, const int* __restrict__ mapping,
                       const int* __restrict__ revmap, const int* __restrict__ timep,
                       const float* __restrict__ W, const float* __restrict__ U,
                       const float* __restrict__ Un,
                       short* __restrict__ Ahi, short* __restrict__ Alo,
                       short* __restrict__ Bg,
                       float* __restrict__ alpha, float* __restrict__ beta,
                       float* __restrict__ part1, float* __restrict__ part2) {
    int blk = blockIdx.x;
    int tid = threadIdx.x;
    if (blk < 4096) {
        // conv_a
        int q = tid & 3;           // q = s*2 + h
        int m = (blk & 255) * 64 + (tid >> 2);
        int kc = blk >> 8;
        int s = q >> 1, h = q & 1;
        int k0 = kc * 32 + s * 16 + h * 4;    // global k of j=0
        const float* src = (k0 < 256) ? (inputs + m * 256 + k0) : (h1 + m * 256 + k0 - 256);
        float4 x0 = *(const float4*)(src);
        float4 x1 = *(const float4*)(src + 8);
        float xs[8] = {x0.x, x0.y, x0.z, x0.w, x1.x, x1.y, x1.z, x1.w};
        bf16x8 hv, lv;
        #pragma unroll
        for (int j = 0; j < 8; j++) {
            short hh = f2bf(xs[j]);
            hv[j] = hh;
            lv[j] = f2bf(xs[j] - bf2f(hh));
        }
        long doff = ((long)kc * 16384 + m) * 32 + q * 8;   // q*8 = s*16 + h*8
        *(bf16x8*)(Ahi + doff) = hv;
        *(bf16x8*)(Alo + doff) = lv;
    } else if (blk < 4416) {
        // conv_b: one thread per (img, g, s, lane), writes hi+lo granules
        int t = (blk - 4096) * 256 + tid;    // 0..81919
        int lane = t & 63;
        int rest = t >> 6;                   // 0..1279
        int gs = rest % 10;                  // g*2+s
        int img = rest / 10;                 // nb*16+kc
        int g = gs >> 1, s = gs & 1;
        int nb = img >> 4, kc = img & 15;
        int u = nb * 32 + (lane & 31);
        int hl = lane >> 5;
        int c = (g < 4) ? g * 256 + u : 256 + u;
        bf16x8 hv, lv;
        #pragma unroll
        for (int j = 0; j < 8; j++) {
            int k = kc * 32 + s * 16 + hl * 4 + (j & 3) + 8 * (j >> 2);
            const float* sp;
            if (k < 256) sp = W + k * 1024 + c;
            else         sp = ((g < 4) ? U : Un) + (k - 256) * 1024 + c;
            float x = *sp;
            short hh = f2bf(x);
            hv[j] = hh;
            lv[j] = f2bf(x - bf2f(hh));
        }
        short* dst = Bg + (long)img * 10240 + gs * 512 + lane * 8;
        *(bf16x8*)dst = hv;              // hi half
        *(bf16x8*)(dst + 5120) = lv;     // lo half
    } else if (blk < 8512) {
        // coef
        int lane = tid & 63;
        int wid  = tid >> 6;
        int b = (blk - 4416) * 4 + wid;
        int t = timep[0];
        int p = revmap[b * TT + t];
        int ng = neighbors[(b * TT + p) * MM + lane];
        int mp = mapping[b * MM + lane];
        int cnt = ng;
        int cp  = (mp < t) ? ng : 0;
        #pragma unroll
        for (int off = 32; off > 0; off >>= 1) {
            cnt += __shfl_xor(cnt, off);
            cp  += __shfl_xor(cp, off);
        }
        if (lane == 0) {
            float a = 0.f, be = 0.f;
            if (cnt > 0) {
                float inv = 1.0f / (float)cnt;
                a  = (float)cp * inv;
                be = (float)(cnt - cp) * inv;
            }
            alpha[b] = a;
            beta[b]  = be;
        }
    } else {
        // colsum partials
        int p = blk - 8512;        // 0..127
        int r0 = p * 128;
        float s1 = 0.f, s2 = 0.f;
        for (int r = 0; r < 128; r++) {
            s1 += h1[(r0 + r) * UU + tid];
            s2 += h2[(r0 + r) * UU + tid];
        }
        part1[p * 256 + tid] = s1;
        part2[p * 256 + tid] = s2;
    }
}

// ---- D2: reduce partials -> hs; v1/v2 = hs @ Un; zero m1/m2 ----
__global__ void k_mid(const float* __restrict__ Un,
                      const float* __restrict__ part1, const float* __restrict__ part2,
                      float* __restrict__ v1, float* __restrict__ v2,
                      float* __restrict__ m12) {
    __shared__ float sh1[256], sh2[256];
    int tid = threadIdx.x;
    if (blockIdx.x == 0 && tid < 512) m12[tid] = 0.f;
    float s1 = 0.f, s2 = 0.f;
    #pragma unroll 8
    for (int p = 0; p < 128; p++) {
        s1 += part1[p * 256 + tid];
        s2 += part2[p * 256 + tid];
    }
    sh1[tid] = s1;
    sh2[tid] = s2;
    __syncthreads();
    int j = blockIdx.x * 256 + tid;
    float a1 = 0.f, a2 = 0.f;
    for (int k = 0; k < 256; k++) {
        float w = Un[k * 1024 + j];
        a1 = fmaf(sh1[k], w, a1);
        a2 = fmaf(sh2[k], w, a2);
    }
    v1[j] = a1;
    v2[j] = a2;
}

// ---- D3: 32x32x16 MFMA GEMM, slot-major ILP + counted vmcnt ----
// grid (128 mb, 8 nb), 256 threads = 4 waves; wave tile 32 rows x 160 virt (5 gates x 32 units)
// Issue-order contract per iteration (pinned by sched_barrier(0)):
//   [5x global_load_lds stage] | [4x A-loads] | s_waitcnt
// so vmcnt(4) at loop top == "all stage ops done, A-loads may fly".
#define STAGE_B(KC, BUF) { \
    const char* _s = (const char*)(Bt + (long)(KC) * 10240); \
    char* _d = (char*)(&Bs[BUF][0]); \
    _Pragma("unroll") \
    for (int _c = 0; _c < 5; _c++) { \
        int _u = wv * 5120 + _c * 1024; \
        __builtin_amdgcn_global_load_lds( \
            (const __attribute__((address_space(1))) void*)(_s + _u + lane * 16), \
            (__attribute__((address_space(3))) void*)(_d + _u), 16, 0, 0); \
    } }

__global__ __launch_bounds__(256) void k_gemm_mfma(
    const short* __restrict__ Ahi, const short* __restrict__ Alo,
    const short* __restrict__ Bg,
    const float* __restrict__ c1p, const float* __restrict__ c2p,
    const float* __restrict__ bias,
    const float* __restrict__ alpha, const float* __restrict__ beta,
    const float* __restrict__ v1, const float* __restrict__ v2,
    float* __restrict__ m1, float* __restrict__ m2,
    float* __restrict__ out_h, float* __restrict__ out_mem)
{
    __shared__ short Bs[2][10240];   // 2 x 20 KB, granule-linear (conflict-free b128)

    const int tid = threadIdx.x;
    const int lane = tid & 63;
    const int wv = tid >> 6;
    const int mb = blockIdx.x;
    const int nb = blockIdx.y;
    const int m0 = mb * 128;
    const short* Bt = Bg + (long)nb * 163840;

    const int col = lane & 31;           // unit / A row within wave tile
    const int hl = lane >> 5;
    const int m = m0 + wv * 32 + col;
    const long abase = (long)m * 32 + hl * 8;   // + kc*524288 ; +16 for s=1

    f32x16 acc[5];
    #pragma unroll
    for (int g = 0; g < 5; g++)
        #pragma unroll
        for (int r = 0; r < 16; r++) acc[g][r] = 0.f;

    // prologue: stage B(0) || A(0) loads, order pinned
    STAGE_B(0, 0);
    __builtin_amdgcn_sched_barrier(0);
    bf16x8 ah0 = *(const bf16x8*)(Ahi + abase);
    bf16x8 ah1 = *(const bf16x8*)(Ahi + abase + 16);
    bf16x8 al0 = *(const bf16x8*)(Alo + abase);
    bf16x8 al1 = *(const bf16x8*)(Alo + abase + 16);
    __builtin_amdgcn_sched_barrier(0);

    for (int kc = 0; kc < 16; kc++) {
        // stage(kc) done (leave the 4 A(kc) loads in flight)
        asm volatile("s_waitcnt vmcnt(4)" ::: "memory");
        __builtin_amdgcn_s_barrier();

        bf16x8 nh0, nh1, nl0, nl1;
        if (kc + 1 < 16) {
            STAGE_B(kc + 1, (kc + 1) & 1);            // +5 vmem
            __builtin_amdgcn_sched_barrier(0);
            long ab = abase + (long)(kc + 1) * 524288;
            nh0 = *(const bf16x8*)(Ahi + ab);         // +4 vmem
            nh1 = *(const bf16x8*)(Ahi + ab + 16);
            nl0 = *(const bf16x8*)(Alo + ab);
            nl1 = *(const bf16x8*)(Alo + ab + 16);
            __builtin_amdgcn_sched_barrier(0);
            asm volatile("s_waitcnt vmcnt(9)" ::: "memory");   // A(kc) done
        } else {
            asm volatile("s_waitcnt vmcnt(0)" ::: "memory");
        }

        const char* bp = (const char*)Bs + (kc & 1) * 20480 + lane * 16;
        // slot-major: 6 slots of 5 independent MFMAs; acc[g] reuse distance = 5
        bf16x8 p0, p1, p2, p3, p4, q0, q1, q2, q3, q4;
        p0 = *(const bf16x8*)(bp + 0 * 1024);        // Bhi s=0, g=0..4
        p1 = *(const bf16x8*)(bp + 2 * 1024);
        p2 = *(const bf16x8*)(bp + 4 * 1024);
        p3 = *(const bf16x8*)(bp + 6 * 1024);
        p4 = *(const bf16x8*)(bp + 8 * 1024);
        q0 = *(const bf16x8*)(bp + 1 * 1024);        // Bhi s=1
        q1 = *(const bf16x8*)(bp + 3 * 1024);
        q2 = *(const bf16x8*)(bp + 5 * 1024);
        q3 = *(const bf16x8*)(bp + 7 * 1024);
        q4 = *(const bf16x8*)(bp + 9 * 1024);

        acc[0] = __builtin_amdgcn_mfma_f32_32x32x16_bf16(ah0, p0, acc[0], 0, 0, 0);
        acc[1] = __builtin_amdgcn_mfma_f32_32x32x16_bf16(ah0, p1, acc[1], 0, 0, 0);
        acc[2] = __builtin_amdgcn_mfma_f32_32x32x16_bf16(ah0, p2, acc[2], 0, 0, 0);
        acc[3] = __builtin_amdgcn_mfma_f32_32x32x16_bf16(ah0, p3, acc[3], 0, 0, 0);
        acc[4] = __builtin_amdgcn_mfma_f32_32x32x16_bf16(ah0, p4, acc[4], 0, 0, 0);

        acc[0] = __builtin_amdgcn_mfma_f32_32x32x16_bf16(al0, p0, acc[0], 0, 0, 0);
        acc[1] = __builtin_amdgcn_mfma_f32_32x32x16_bf16(al0, p1, acc[1], 0, 0, 0);
        acc[2] = __builtin_amdgcn_mfma_f32_32x32x16_bf16(al0, p2, acc[2], 0, 0, 0);
        acc[3] = __builtin_amdgcn_mfma_f32_32x32x16_bf16(al0, p3, acc[3], 0, 0, 0);
        acc[4] = __builtin_amdgcn_mfma_f32_32x32x16_bf16(al0, p4, acc[4], 0, 0, 0);

        // overwrite P with Blo s=0
        p0 = *(const bf16x8*)(bp + 10240 + 0 * 1024);
        p1 = *(const bf16x8*)(bp + 10240 + 2 * 1024);
        p2 = *(const bf16x8*)(bp + 10240 + 4 * 1024);
        p3 = *(const bf16x8*)(bp + 10240 + 6 * 1024);
        p4 = *(const bf16x8*)(bp + 10240 + 8 * 1024);

        acc[0] = __builtin_amdgcn_mfma_f32_32x32x16_bf16(ah1, q0, acc[0], 0, 0, 0);
        acc[1] = __builtin_amdgcn_mfma_f32_32x32x16_bf16(ah1, q1, acc[1], 0, 0, 0);
        acc[2] = __builtin_amdgcn_mfma_f32_32x32x16_bf16(ah1, q2, acc[2], 0, 0, 0);
        acc[3] = __builtin_amdgcn_mfma_f32_32x32x16_bf16(ah1, q3, acc[3], 0, 0, 0);
        acc[4] = __builtin_amdgcn_mfma_f32_32x32x16_bf16(ah1, q4, acc[4], 0, 0, 0);

        acc[0] = __builtin_amdgcn_mfma_f32_32x32x16_bf16(al1, q0, acc[0], 0, 0, 0);
        acc[1] = __builtin_amdgcn_mfma_f32_32x32x16_bf16(al1, q1, acc[1], 0, 0, 0);
        acc[2] = __builtin_amdgcn_mfma_f32_32x32x16_bf16(al1, q2, acc[2], 0, 0, 0);
        acc[3] = __builtin_amdgcn_mfma_f32_32x32x16_bf16(al1, q3, acc[3], 0, 0, 0);
        acc[4] = __builtin_amdgcn_mfma_f32_32x32x16_bf16(al1, q4, acc[4], 0, 0, 0);

        // overwrite Q with Blo s=1
        q0 = *(const bf16x8*)(bp + 10240 + 1 * 1024);
        q1 = *(const bf16x8*)(bp + 10240 + 3 * 1024);
        q2 = *(const bf16x8*)(bp + 10240 + 5 * 1024);
        q3 = *(const bf16x8*)(bp + 10240 + 7 * 1024);
        q4 = *(const bf16x8*)(bp + 10240 + 9 * 1024);

        acc[0] = __builtin_amdgcn_mfma_f32_32x32x16_bf16(ah0, p0, acc[0], 0, 0, 0);
        acc[1] = __builtin_amdgcn_mfma_f32_32x32x16_bf16(ah0, p1, acc[1], 0, 0, 0);
        acc[2] = __builtin_amdgcn_mfma_f32_32x32x16_bf16(ah0, p2, acc[2], 0, 0, 0);
        acc[3] = __builtin_amdgcn_mfma_f32_32x32x16_bf16(ah0, p3, acc[3], 0, 0, 0);
        acc[4] = __builtin_amdgcn_mfma_f32_32x32x16_bf16(ah0, p4, acc[4], 0, 0, 0);

        acc[0] = __builtin_amdgcn_mfma_f32_32x32x16_bf16(ah1, q0, acc[0], 0, 0, 0);
        acc[1] = __builtin_amdgcn_mfma_f32_32x32x16_bf16(ah1, q1, acc[1], 0, 0, 0);
        acc[2] = __builtin_amdgcn_mfma_f32_32x32x16_bf16(ah1, q2, acc[2], 0, 0, 0);
        acc[3] = __builtin_amdgcn_mfma_f32_32x32x16_bf16(ah1, q3, acc[3], 0, 0, 0);
        acc[4] = __builtin_amdgcn_mfma_f32_32x32x16_bf16(ah1, q4, acc[4], 0, 0, 0);

        if (kc + 1 < 16) { ah0 = nh0; ah1 = nh1; al0 = nl0; al1 = nl1; }
    }

    // ---- fused epilogue; C/D: col=lane&31, row=(r&3)+8*(r>>2)+4*(lane>>5) ----
    int u = nb * 32 + col;
    float bi = bias[u], bfv = bias[256 + u], bc = bias[512 + u], bo = bias[768 + u];
    float v1i = v1[u], v1c = v1[512 + u], v1o = v1[768 + u];
    float v2i = v2[u], v2c = v2[512 + u], v2o = v2[768 + u];

    float pm1 = 0.f, pm2 = 0.f;
    #pragma unroll
    for (int r = 0; r < 16; r++) {
        int row = (r & 3) + 8 * (r >> 2) + 4 * hl;
        int b = m0 + wv * 32 + row;
        float al = alpha[b], be = beta[b];
        float c1 = c1p[b * 256 + u];
        float c2 = c2p[b * 256 + u];
        float zi  = acc[0][r] + bi + al * v1i + be * v2i;
        float zf  = acc[1][r] + bfv;
        float zc  = acc[2][r] + bc + al * v1c + be * v2c;
        float zo  = acc[3][r] + bo + al * v1o + be * v2o;
        float zfa = acc[4][r] + bfv;
        float ig = hsig(zi), fg = hsig(zf), og = hsig(zo), fav = hsig(zfa);
        float cg = tanhf(zc);
        out_mem[b * 256 + u] = fg * c1 + ig * cg;
        out_h[b * 256 + u]  = og;
        pm1 += fav * c1;
        pm2 += fav * c2;
    }

    // lanes l and l^32 share the same unit; reduce, then cross-wave via LDS
    pm1 += __shfl_xor(pm1, 32);
    pm2 += __shfl_xor(pm2, 32);
    __syncthreads();
    float* red = (float*)&Bs[0][0];   // [wave][d][u] = 4*2*32 floats
    if (hl == 0) {
        red[(wv * 2 + 0) * 32 + col] = pm1;
        red[(wv * 2 + 1) * 32 + col] = pm2;
    }
    __syncthreads();
    if (tid < 64) {
        int d = tid >> 5, ui = tid & 31;
        float s = 0.f;
        #pragma unroll
        for (int w = 0; w < 4; w++) s += red[(w * 2 + d) * 32 + ui];
        atomicAdd(((d == 0) ? m1 : m2) + nb * 32 + ui, s);
    }
}

// ---- D4: memory = alpha*m1 + beta*m2 + mem_partial ; h = o * tanh(memory) ----
__global__ void k_final(const float* __restrict__ alpha, const float* __restrict__ beta,
                        const float* __restrict__ m1, const float* __restrict__ m2,
                        float* __restrict__ out_h, float* __restrict__ out_mem) {
    int idx = blockIdx.x * 256 + threadIdx.x;
    int b  = idx >> 6;
    int uv = idx & 63;
    float4 mp = ((const float4*)out_mem)[idx];
    float4 ov = ((const float4*)out_h)[idx];
    float al = alpha[b], be = beta[b];
    float4 m1v = ((const float4*)m1)[uv];
    float4 m2v = ((const float4*)m2)[uv];
    float4 mem, h;
    mem.x = fmaf(al, m1v.x, fmaf(be, m2v.x, mp.x)); h.x = ov.x * tanhf(mem.x);
    mem.y = fmaf(al, m1v.y, fmaf(be, m2v.y, mp.y)); h.y = ov.y * tanhf(mem.y);
    mem.z = fmaf(al, m1v.z, fmaf(be, m2v.z, mp.z)); h.z = ov.z * tanhf(mem.z);
    mem.w = fmaf(al, m1v.w, fmaf(be, m2v.w, mp.w)); h.w = ov.w * tanhf(mem.w);
    ((float4*)out_mem)[idx] = mem;
    ((float4*)out_h)[idx]   = h;
}

extern "C" void kernel_launch(void* const* d_in, const int* in_sizes, int n_in,
                              void* d_out, int out_size, void* d_ws, size_t ws_size,
                              hipStream_t stream) {
    const float* inputs   = (const float*)d_in[0];
    const float* h_tm1    = (const float*)d_in[1];
    const float* c_tm1    = (const float*)d_in[2];
    const float* h_tm2    = (const float*)d_in[3];
    const float* c_tm2    = (const float*)d_in[4];
    const int*   neighbors= (const int*)d_in[5];
    const int*   mapping  = (const int*)d_in[6];
    const int*   revmap   = (const int*)d_in[7];
    const int*   timep    = (const int*)d_in[8];
    const float* W        = (const float*)d_in[9];
    const float* Uw       = (const float*)d_in[10];
    const float* Un       = (const float*)d_in[11];
    const float* bias     = (const float*)d_in[12];

    float* ws    = (float*)d_ws;
    float* alpha = ws + WS_ALPHA;
    float* beta  = ws + WS_BETA;
    float* m1    = ws + WS_M1;
    float* m2    = ws + WS_M2;
    float* v1    = ws + WS_V1;
    float* v2    = ws + WS_V2;
    float* part1 = ws + WS_PART1;
    float* part2 = ws + WS_PART2;

    short* Ahi = (short*)((char*)d_ws + WS_BF16_BYTE);
    short* Alo = Ahi + 8388608;
    short* Bg  = Alo + 8388608;

    float* out_h   = (float*)d_out;
    float* out_mem = out_h + BB * UU;

    k_prep<<<8640, 256, 0, stream>>>(inputs, h_tm1, h_tm2, neighbors, mapping, revmap,
                                     timep, W, Uw, Un, Ahi, Alo, Bg, alpha, beta,
                                     part1, part2);
    k_mid<<<4, 256, 0, stream>>>(Un, part1, part2, v1, v2, m1);

    dim3 g3(128, 8);
    k_gemm_mfma<<<g3, 256, 0, stream>>>(Ahi, Alo, Bg, c_tm1, c_tm2, bias,
                                        alpha, beta, v1, v2, m1, m2, out_h, out_mem);

    k_final<<<BB * UU / 4 / 256, 256, 0, stream>>>(alpha, beta, m1, m2, out_h, out_mem);
}